// Round 2
// baseline (166.407 us; speedup 1.0000x reference)
//
#include <hip/hip_runtime.h>
#include <math.h>

// One 64-lane wave per agent. Lanes: lc = lane&31 -> window column (0..26 used),
// lane>>5 -> row parity (2 rows per loop iteration).
__global__ __launch_bounds__(256) void nsp_forces(
    const float* __restrict__ cstep,
    const float* __restrict__ fframe,
    const float* __restrict__ cvel,
    const int*   __restrict__ smap,
    float* __restrict__ out,
    int N, int Hm, int Wm)
{
    const int gid  = blockIdx.x * blockDim.x + threadIdx.x;
    const int n    = gid >> 6;
    const int lane = threadIdx.x & 63;
    if (n >= N) return;

    const float ori_r = cstep[2*n+0] + fframe[2*n+0];
    const float ori_c = cstep[2*n+1] + fframe[2*n+1];
    const float vr = cvel[2*n+0], vc = cvel[2*n+1];
    const float sgr = (vr > 0.f) ? 1.f : ((vr < 0.f) ? -1.f : 0.f);
    const float sgc = (vc > 0.f) ? 1.f : ((vc < 0.f) ? -1.f : 0.f);

    // replicate the reference's f32 arithmetic exactly
    const int r0 = (int)floorf(ori_r);
    const int c0 = (int)floorf(ori_c);
    const int r1 = (int)floorf(ori_r + sgr * 25.0f);
    const int c1 = (int)floorf(ori_c + sgc * 25.0f);

    const int rmin = min(r0, r1), rmax = max(r0, r1);
    const int cmin = min(c0, c1), cmax = max(c0, c1);
    const bool deg_r = (r0 == r1), deg_c = (c0 == c1);
    const bool both  = deg_r && deg_c;

    // mask: lr < (rmax-rmin) (or lr==0 if degenerate); lr ranges over [0,27)
    const int nr = deg_r ? 1 : min(rmax - rmin, 27);
    const int nc = deg_c ? 1 : min(cmax - cmin, 27);

    const int lc   = lane & 31;   // window column handled by this lane
    const int rofs = lane >> 5;   // 0/1 row parity

    int cnt5 = 0, sr5 = 0, sc5 = 0;
    int cnt3 = 0, sr3 = 0, sc3 = 0;
    int cnt4 = 0, sr4 = 0, sc4 = 0;

    const int  ccol = cmin + lc;
    const bool cok  = (lc < nc) && (ccol >= 0) && (ccol < Wm);

    if (!both && cok) {
        const int* __restrict__ p = smap + (size_t)ccol;
        for (int rb = rofs; rb < nr; rb += 2) {
            const int rrow = rmin + rb;
            if (rrow < 0 || rrow >= Hm) continue;
            const int v = p[(size_t)rrow * (size_t)Wm];
            const int m5 = (v == 5), m3 = (v == 3), m4 = (v == 4);
            cnt5 += m5; sr5 += m5 ? rb : 0; sc5 += m5 ? lc : 0;
            cnt3 += m3; sr3 += m3 ? rb : 0; sc3 += m3 ? lc : 0;
            cnt4 += m4; sr4 += m4 ? rb : 0; sc4 += m4 ? lc : 0;
        }
    }

    // full-wave butterfly reduction (all lanes end with the totals)
    #pragma unroll
    for (int o = 32; o; o >>= 1) {
        cnt5 += __shfl_xor(cnt5, o); sr5 += __shfl_xor(sr5, o); sc5 += __shfl_xor(sc5, o);
        cnt3 += __shfl_xor(cnt3, o); sr3 += __shfl_xor(sr3, o); sc3 += __shfl_xor(sc3, o);
        cnt4 += __shfl_xor(cnt4, o); sr4 += __shfl_xor(sr4, o); sc4 += __shfl_xor(sc4, o);
    }

    if (lane == 0) {
        const int   cnts[3] = {cnt5, cnt3, cnt4};
        const int   srs[3]  = {sr5,  sr3,  sr4};
        const int   scs[3]  = {sc5,  sc3,  sc4};
        const float wts[3]  = {1.0f, 1.0f, 1.5f};
        const float p1s[3]  = {1.0f, 0.0f, 0.0f};

        float Fr = 0.0f, Fc = 0.0f;
        #pragma unroll
        for (int i = 0; i < 3; ++i) {
            const float denom  = fmaxf((float)cnts[i], 1.0f);
            const float mean_r = (float)srs[i] / denom;
            const float mean_c = (float)scs[i] / denom;
            float fr, fc;
            if (deg_r && !deg_c) {
                const float disA = (c0 < c1) ? mean_c : (25.0f - mean_c);
                const float mag  = (disA != 0.0f) ? (wts[i] * 100.0f / disA) : 0.0f;
                fr = 0.0f;
                fc = (c0 < c1) ? -mag : mag;
            } else if (!deg_r && deg_c) {
                const float disB = (r0 < r1) ? (mean_r + p1s[i]) : (25.0f - mean_r);
                const float mag  = (disB != 0.0f) ? (wts[i] * 100.0f / disB) : 0.0f;
                fr = (r0 < r1) ? -mag : mag;
                fc = 0.0f;
            } else {
                const float crn_r = (r0 < r1) ? 0.0f : 25.0f;
                const float crn_c = (c0 < c1) ? 0.0f : 25.0f;
                const float dr = mean_r - crn_r;
                const float dc = mean_c - crn_c;
                const float disC = sqrtf(dr * dr + dc * dc);
                if (disC != 0.0f) {
                    const float s = -(wts[i] * 100.0f) / (disC * disC);
                    fr = s * dr; fc = s * dc;
                } else {
                    fr = 0.0f; fc = 0.0f;
                }
            }
            if (cnts[i] > 0 && !both) { Fr += fr; Fc += fc; }
        }
        out[2*n+0] = Fr;
        out[2*n+1] = Fc;
    }
}

extern "C" void kernel_launch(void* const* d_in, const int* in_sizes, int n_in,
                              void* d_out, int out_size, void* d_ws, size_t ws_size,
                              hipStream_t stream) {
    const float* cstep  = (const float*)d_in[0];
    const float* fframe = (const float*)d_in[1];
    const float* cvel   = (const float*)d_in[2];
    const int*   smap   = (const int*)d_in[3];
    float* out = (float*)d_out;

    const int N  = in_sizes[0] / 2;
    const int Hm = 4096, Wm = 4096;   // semantic_map is H x W per reference

    const int threads = 256;                 // 4 waves/block = 4 agents/block
    const int agentsPerBlock = threads / 64;
    const int blocks = (N + agentsPerBlock - 1) / agentsPerBlock;
    hipLaunchKernelGGL(nsp_forces, dim3(blocks), dim3(threads), 0, stream,
                       cstep, fframe, cvel, smap, out, N, Hm, Wm);
}

// Round 4
// 151.737 us; speedup vs baseline: 1.0967x; 1.0967x over previous
//
#include <hip/hip_runtime.h>
#include <math.h>

// One 64-lane wave per agent. lc = lane&31 -> window column, rho = lane>>5 ->
// row parity (rows rb = rho, rho+2, ... processed over a uniform trip count T).
//
// Match accumulation uses the prefix-carry trick:
//   c += (v==L); s += c;   =>  sum_j j*m_j = T*c - s   (uniform T, masked tail)
// so per element per label is 3 VALU (cmp, addc, add). Column sums are
// lane-constant: sc = lc * c, computed once after the loop.
__global__ __launch_bounds__(256) void nsp_forces(
    const float* __restrict__ cstep,
    const float* __restrict__ fframe,
    const float* __restrict__ cvel,
    const int*   __restrict__ smap,
    float* __restrict__ out,
    int N, int Hm, int Wm)
{
    const int gid  = blockIdx.x * blockDim.x + threadIdx.x;
    const int n    = gid >> 6;
    const int lane = threadIdx.x & 63;
    if (n >= N) return;

    const float ori_r = cstep[2*n+0] + fframe[2*n+0];
    const float ori_c = cstep[2*n+1] + fframe[2*n+1];
    const float vr = cvel[2*n+0], vc = cvel[2*n+1];
    const float sgr = (vr > 0.f) ? 1.f : ((vr < 0.f) ? -1.f : 0.f);
    const float sgc = (vc > 0.f) ? 1.f : ((vc < 0.f) ? -1.f : 0.f);

    // replicate the reference's f32 arithmetic exactly
    const int r0 = (int)floorf(ori_r);
    const int c0 = (int)floorf(ori_c);
    const int r1 = (int)floorf(ori_r + sgr * 25.0f);
    const int c1 = (int)floorf(ori_c + sgc * 25.0f);

    const int rmin = min(r0, r1), rmax = max(r0, r1);
    const int cmin = min(c0, c1), cmax = max(c0, c1);
    const bool deg_r = (r0 == r1), deg_c = (c0 == c1);
    const bool both  = deg_r && deg_c;

    // mask is lr < (rmax-rmin) (strict), so at most 26 rows/cols; degenerate -> 1
    const int nr = deg_r ? 1 : min(rmax - rmin, 27);
    const int nc = deg_c ? 1 : min(cmax - cmin, 27);

    const int lc  = lane & 31;
    const int rho = lane >> 5;

    const int  ccol    = cmin + lc;
    const bool cok     = (lc < nc) && (ccol >= 0) && (ccol < Wm);
    const int  ccol_cl = min(max(ccol, 0), Wm - 1);   // safe address, masked if !cok

    const int T      = (nr + 1) >> 1;                    // wave-uniform trip count
    const int t_lane = cok ? ((nr - rho + 1) >> 1) : 0;  // valid iterations this lane

    int c5 = 0, s5 = 0, c3 = 0, s3 = 0, c4 = 0, s4 = 0;

    if (!both) {
        const bool rows_in = (rmin >= 0) && (rmin + nr <= Hm);  // wave-uniform
        if (rows_in) {
            // fast path: no per-iteration row checks, pointer-increment addressing
            const int* p = smap + (size_t)(rmin + rho) * (size_t)Wm + ccol_cl;
            const ptrdiff_t stride = 2 * (ptrdiff_t)Wm;
            #pragma unroll 2
            for (int j = 0; j < T; ++j) {
                int v = *p;
                p += stride;
                v = (j < t_lane) ? v : -1;   // mask tail / !cok lanes
                c5 += (v == 5); s5 += c5;
                c3 += (v == 3); s3 += c3;
                c4 += (v == 4); s4 += c4;
            }
        } else {
            // rare slow path: clamp row address, mask OOB rows
            for (int j = 0; j < T; ++j) {
                const int rrow = rmin + rho + 2 * j;
                const int rcl  = min(max(rrow, 0), Hm - 1);
                int v = smap[(size_t)rcl * (size_t)Wm + ccol_cl];
                const bool ok = (j < t_lane) && (rrow >= 0) && (rrow < Hm);
                v = ok ? v : -1;
                c5 += (v == 5); s5 += c5;
                c3 += (v == 3); s3 += c3;
                c4 += (v == 4); s4 += c4;
            }
        }
    }

    // per-lane totals: cnt = c; sum_rb = 2*(T*c - s) + rho*c; sum_col = lc*c
    // pack (cnt, sum_rb) into one word: cnt <= 676 (10 bits), sum_rb total <= 16900
    const unsigned sr5l = (unsigned)(2 * (T * c5 - s5) + rho * c5);
    const unsigned sr3l = (unsigned)(2 * (T * c3 - s3) + rho * c3);
    const unsigned sr4l = (unsigned)(2 * (T * c4 - s4) + rho * c4);
    unsigned q5 = (unsigned)c5 | (sr5l << 10);
    unsigned q3 = (unsigned)c3 | (sr3l << 10);
    unsigned q4 = (unsigned)c4 | (sr4l << 10);
    int sc5 = lc * c5, sc3 = lc * c3, sc4 = lc * c4;

    #pragma unroll
    for (int o = 32; o; o >>= 1) {
        q5  += __shfl_xor(q5, o);  q3  += __shfl_xor(q3, o);  q4  += __shfl_xor(q4, o);
        sc5 += __shfl_xor(sc5, o); sc3 += __shfl_xor(sc3, o); sc4 += __shfl_xor(sc4, o);
    }

    if (lane == 0) {
        const int   cnts[3] = {(int)(q5 & 1023u), (int)(q3 & 1023u), (int)(q4 & 1023u)};
        const int   srs[3]  = {(int)(q5 >> 10),   (int)(q3 >> 10),   (int)(q4 >> 10)};
        const int   scs[3]  = {sc5, sc3, sc4};
        const float wts[3]  = {1.0f, 1.0f, 1.5f};
        const float p1s[3]  = {1.0f, 0.0f, 0.0f};

        float Fr = 0.0f, Fc = 0.0f;
        #pragma unroll
        for (int i = 0; i < 3; ++i) {
            const float denom  = fmaxf((float)cnts[i], 1.0f);
            const float mean_r = (float)srs[i] / denom;
            const float mean_c = (float)scs[i] / denom;
            float fr, fc;
            if (deg_r && !deg_c) {
                const float disA = (c0 < c1) ? mean_c : (25.0f - mean_c);
                const float mag  = (disA != 0.0f) ? (wts[i] * 100.0f / disA) : 0.0f;
                fr = 0.0f;
                fc = (c0 < c1) ? -mag : mag;
            } else if (!deg_r && deg_c) {
                const float disB = (r0 < r1) ? (mean_r + p1s[i]) : (25.0f - mean_r);
                const float mag  = (disB != 0.0f) ? (wts[i] * 100.0f / disB) : 0.0f;
                fr = (r0 < r1) ? -mag : mag;
                fc = 0.0f;
            } else {
                const float crn_r = (r0 < r1) ? 0.0f : 25.0f;
                const float crn_c = (c0 < c1) ? 0.0f : 25.0f;
                const float dr = mean_r - crn_r;
                const float dc = mean_c - crn_c;
                const float disC = sqrtf(dr * dr + dc * dc);
                if (disC != 0.0f) {
                    const float s = -(wts[i] * 100.0f) / (disC * disC);
                    fr = s * dr; fc = s * dc;
                } else {
                    fr = 0.0f; fc = 0.0f;
                }
            }
            if (cnts[i] > 0 && !both) { Fr += fr; Fc += fc; }
        }
        out[2*n+0] = Fr;
        out[2*n+1] = Fc;
    }
}

extern "C" void kernel_launch(void* const* d_in, const int* in_sizes, int n_in,
                              void* d_out, int out_size, void* d_ws, size_t ws_size,
                              hipStream_t stream) {
    const float* cstep  = (const float*)d_in[0];
    const float* fframe = (const float*)d_in[1];
    const float* cvel   = (const float*)d_in[2];
    const int*   smap   = (const int*)d_in[3];
    float* out = (float*)d_out;

    const int N  = in_sizes[0] / 2;
    const int Hm = 4096, Wm = 4096;

    const int threads = 256;                 // 4 waves/block = 4 agents/block
    const int agentsPerBlock = threads / 64;
    const int blocks = (N + agentsPerBlock - 1) / agentsPerBlock;
    hipLaunchKernelGGL(nsp_forces, dim3(blocks), dim3(threads), 0, stream,
                       cstep, fframe, cvel, smap, out, N, Hm, Wm);
}

// Round 5
// 149.873 us; speedup vs baseline: 1.1103x; 1.0124x over previous
//
#include <hip/hip_runtime.h>
#include <math.h>

#define HM 4096
#define WM 4096

struct AgentGeom {
    int r0, c0, r1, c1;
    int rmin, cmin;
    int nr, nc;
    bool deg_r, deg_c, both;
};

__device__ __forceinline__ AgentGeom agent_geom(const float* __restrict__ cstep,
                                                const float* __restrict__ fframe,
                                                const float* __restrict__ cvel, int n)
{
    AgentGeom g;
    const float ori_r = cstep[2*n+0] + fframe[2*n+0];
    const float ori_c = cstep[2*n+1] + fframe[2*n+1];
    const float vr = cvel[2*n+0], vc = cvel[2*n+1];
    const float sgr = (vr > 0.f) ? 1.f : ((vr < 0.f) ? -1.f : 0.f);
    const float sgc = (vc > 0.f) ? 1.f : ((vc < 0.f) ? -1.f : 0.f);
    g.r0 = (int)floorf(ori_r);
    g.c0 = (int)floorf(ori_c);
    g.r1 = (int)floorf(ori_r + sgr * 25.0f);
    g.c1 = (int)floorf(ori_c + sgc * 25.0f);
    g.rmin = min(g.r0, g.r1);
    g.cmin = min(g.c0, g.c1);
    g.deg_r = (g.r0 == g.r1);
    g.deg_c = (g.c0 == g.c1);
    g.both  = g.deg_r && g.deg_c;
    g.nr = g.deg_r ? 1 : min(max(g.r0, g.r1) - g.rmin, 27);
    g.nc = g.deg_c ? 1 : min(max(g.c0, g.c1) - g.cmin, 27);
    return g;
}

// Identical float math to the validated round-2/4 epilogue (absmax 0.0625).
__device__ __forceinline__ void force_from_counts(const AgentGeom& g,
    const int cnts[3], const int srs[3], const int scs[3], float& Fr, float& Fc)
{
    const float wts[3] = {1.0f, 1.0f, 1.5f};
    const float p1s[3] = {1.0f, 0.0f, 0.0f};
    Fr = 0.0f; Fc = 0.0f;
    #pragma unroll
    for (int i = 0; i < 3; ++i) {
        const float denom  = fmaxf((float)cnts[i], 1.0f);
        const float mean_r = (float)srs[i] / denom;
        const float mean_c = (float)scs[i] / denom;
        float fr, fc;
        if (g.deg_r && !g.deg_c) {
            const float disA = (g.c0 < g.c1) ? mean_c : (25.0f - mean_c);
            const float mag  = (disA != 0.0f) ? (wts[i] * 100.0f / disA) : 0.0f;
            fr = 0.0f;
            fc = (g.c0 < g.c1) ? -mag : mag;
        } else if (!g.deg_r && g.deg_c) {
            const float disB = (g.r0 < g.r1) ? (mean_r + p1s[i]) : (25.0f - mean_r);
            const float mag  = (disB != 0.0f) ? (wts[i] * 100.0f / disB) : 0.0f;
            fr = (g.r0 < g.r1) ? -mag : mag;
            fc = 0.0f;
        } else {
            const float crn_r = (g.r0 < g.r1) ? 0.0f : 25.0f;
            const float crn_c = (g.c0 < g.c1) ? 0.0f : 25.0f;
            const float dr = mean_r - crn_r;
            const float dc = mean_c - crn_c;
            const float disC = sqrtf(dr * dr + dc * dc);
            if (disC != 0.0f) {
                const float s = -(wts[i] * 100.0f) / (disC * disC);
                fr = s * dr; fc = s * dc;
            } else { fr = 0.0f; fc = 0.0f; }
        }
        if (cnts[i] > 0 && !g.both) { Fr += fr; Fc += fc; }
    }
}

// 2 agents per 64-lane wave. Within a 32-lane half: cg = l5&7 -> 4-int column
// group (8 groups cover the aligned 32-col span), rho = l5>>3 -> row parity
// (rows rb = rho + 4j). SWAR: pack 4 map values (0..5) into one register's
// bytes; label match via 3-bit patterns; per-byte counters W and packed
// prefix S give counts + row sums; column sums from end-only W unpack.
__global__ __launch_bounds__(256) void nsp_gather(
    const float* __restrict__ cstep, const float* __restrict__ fframe,
    const float* __restrict__ cvel, const int* __restrict__ smap,
    int* __restrict__ ws, float* __restrict__ out, int fused, int N)
{
    const int wave = (blockIdx.x * blockDim.x + threadIdx.x) >> 6;
    const int lane = threadIdx.x & 63;
    const int half = lane >> 5;
    const int l5   = lane & 31;
    const int n    = wave * 2 + half;
    const bool live = (n < N);
    const int n_eff = live ? n : (N - 1);

    const AgentGeom g = agent_geom(cstep, fframe, cvel, n_eff);

    const int cg  = l5 & 7;        // column group of 4 ints
    const int rho = l5 >> 3;       // row parity 0..3, rows advance by 4
    const int a   = g.cmin & ~3;   // 16B-aligned column base (floor to mult of 4)
    const int d   = g.cmin - a;    // 0..3

    // invalid-byte mask: window-col out of mask range OR map-col out of bounds
    unsigned B = 0;
    #pragma unroll
    for (int k = 0; k < 4; ++k) {
        const int wc  = cg * 4 + k - d;       // window column index
        const int col = a + cg * 4 + k;       // map column
        const bool bad = ((unsigned)wc >= (unsigned)g.nc) ||
                         ((unsigned)col >= (unsigned)WM);
        B |= bad ? (0xFFu << (8 * k)) : 0u;
    }

    const int T_half = (g.nr + 3) >> 2;                             // uniform per half
    const int t_lane = (rho < g.nr) ? ((g.nr - rho + 3) >> 2) : 0;  // valid iters
    const int T_oth  = __shfl_xor(T_half, 32);
    const int T_wave = max(T_half, T_oth);

    const bool fastl = (g.rmin >= 0) && (g.rmin + 28 <= HM) &&
                       (a >= 0) && (a + 32 <= WM);
    const bool fastw = __all(fastl ? 1 : 0);

    unsigned W5 = 0, S5 = 0, W3 = 0, S3 = 0, W4 = 0, S4 = 0;
    const unsigned k01 = 0x01010101u;

    if (fastw) {
        const int lane_off = rho * WM + a + cg * 4;   // loop-invariant, per-lane
        for (int j = 0; j < T_wave; ++j) {
            const int4 v = *reinterpret_cast<const int4*>(
                smap + (size_t)((g.rmin + 4 * j) * WM + lane_off));
            unsigned y = ((((((unsigned)v.w << 8) | (unsigned)v.z) << 8)
                           | (unsigned)v.y) << 8) | (unsigned)v.x;
            y |= B;
            y = (j < t_lane) ? y : 0xFFFFFFFFu;
            const unsigned b1 = y >> 1, b2 = y >> 2;
            const unsigned m5 = ( y & ~b1 &  b2) & k01;   // 101
            const unsigned m3 = ( y &  b1 & ~b2) & k01;   // 011
            const unsigned m4 = (~y & ~b1 &  b2) & k01;   // 100
            W5 += m5; S5 += W5;
            W3 += m3; S3 += W3;
            W4 += m4; S4 += W4;
        }
    } else {
        // rare edge path: per-element clamped loads, same accumulation
        for (int j = 0; j < T_wave; ++j) {
            const int rrow = g.rmin + rho + 4 * j;
            const int rcl  = min(max(rrow, 0), HM - 1);
            unsigned y = 0;
            #pragma unroll
            for (int k = 0; k < 4; ++k) {
                const int col  = a + cg * 4 + k;
                const int colc = min(max(col, 0), WM - 1);
                const unsigned vv = (unsigned)smap[(size_t)rcl * WM + colc];
                y |= vv << (8 * k);
            }
            y |= B;
            const bool rok = (j < t_lane) && ((unsigned)rrow < (unsigned)HM);
            y = rok ? y : 0xFFFFFFFFu;
            const unsigned b1 = y >> 1, b2 = y >> 2;
            const unsigned m5 = ( y & ~b1 &  b2) & k01;
            const unsigned m3 = ( y &  b1 & ~b2) & k01;
            const unsigned m4 = (~y & ~b1 &  b2) & k01;
            W5 += m5; S5 += W5;
            W3 += m3; S3 += W3;
            W4 += m4; S4 += W4;
        }
    }

    // per-lane totals. bytesum ok: W bytes <= 7, S bytes <= 28 (T<=7)
    #define BYTESUM(x) ((int)(((x) * 0x01010101u) >> 24))
    const int c5 = BYTESUM(W5), c3 = BYTESUM(W3), c4 = BYTESUM(W4);
    const int rs5 = rho * c5 + 4 * (T_wave * c5 - BYTESUM(S5));
    const int rs3 = rho * c3 + 4 * (T_wave * c3 - BYTESUM(S3));
    const int rs4 = rho * c4 + 4 * (T_wave * c4 - BYTESUM(S4));
    #define KSUM(W) ((int)(((W) >> 8) & 0xFFu) + 2 * (int)(((W) >> 16) & 0xFFu) + 3 * (int)((W) >> 24))
    const int cbase = cg * 4 - d;                 // first window-col of this group
    const int cs5 = cbase * c5 + KSUM(W5);
    const int cs3 = cbase * c3 + KSUM(W3);
    const int cs4v = cbase * c4 + KSUM(W4);

    // pack: q = cnt(10b) | rowsum(22b); scp = colsum5(15b) | colsum3<<15
    unsigned q5 = (unsigned)c5 | ((unsigned)rs5 << 10);
    unsigned q3 = (unsigned)c3 | ((unsigned)rs3 << 10);
    unsigned q4 = (unsigned)c4 | ((unsigned)rs4 << 10);
    unsigned scp = (unsigned)cs5 | ((unsigned)cs3 << 15);
    int      sc4 = cs4v;

    #pragma unroll
    for (int o = 1; o <= 16; o <<= 1) {
        q5  += __shfl_xor(q5, o);
        q3  += __shfl_xor(q3, o);
        q4  += __shfl_xor(q4, o);
        scp += __shfl_xor(scp, o);
        sc4 += __shfl_xor(sc4, o);
    }

    if (l5 == 0 && live) {
        if (!fused) {
            int4* w4 = reinterpret_cast<int4*>(ws + (size_t)n * 8);
            *w4 = make_int4((int)q5, (int)q3, (int)q4, (int)scp);
            ws[(size_t)n * 8 + 4] = sc4;
        } else {
            const int cnts[3] = {(int)(q5 & 1023u), (int)(q3 & 1023u), (int)(q4 & 1023u)};
            const int srs[3]  = {(int)(q5 >> 10),   (int)(q3 >> 10),   (int)(q4 >> 10)};
            const int scs[3]  = {(int)(scp & 0x7FFFu), (int)(scp >> 15), sc4};
            float Fr, Fc;
            force_from_counts(g, cnts, srs, scs, Fr, Fc);
            out[2*n+0] = Fr;
            out[2*n+1] = Fc;
        }
    }
}

// one thread per agent: unpack totals, recompute geometry, force math
__global__ __launch_bounds__(256) void nsp_force(
    const float* __restrict__ cstep, const float* __restrict__ fframe,
    const float* __restrict__ cvel, const int* __restrict__ ws,
    float* __restrict__ out, int N)
{
    const int n = blockIdx.x * blockDim.x + threadIdx.x;
    if (n >= N) return;
    const AgentGeom g = agent_geom(cstep, fframe, cvel, n);
    const int4 w4 = *reinterpret_cast<const int4*>(ws + (size_t)n * 8);
    const int sc4 = ws[(size_t)n * 8 + 4];
    const unsigned q5 = (unsigned)w4.x, q3 = (unsigned)w4.y,
                   q4 = (unsigned)w4.z, scp = (unsigned)w4.w;
    const int cnts[3] = {(int)(q5 & 1023u), (int)(q3 & 1023u), (int)(q4 & 1023u)};
    const int srs[3]  = {(int)(q5 >> 10),   (int)(q3 >> 10),   (int)(q4 >> 10)};
    const int scs[3]  = {(int)(scp & 0x7FFFu), (int)(scp >> 15), sc4};
    float Fr, Fc;
    force_from_counts(g, cnts, srs, scs, Fr, Fc);
    out[2*n+0] = Fr;
    out[2*n+1] = Fc;
}

extern "C" void kernel_launch(void* const* d_in, const int* in_sizes, int n_in,
                              void* d_out, int out_size, void* d_ws, size_t ws_size,
                              hipStream_t stream) {
    const float* cstep  = (const float*)d_in[0];
    const float* fframe = (const float*)d_in[1];
    const float* cvel   = (const float*)d_in[2];
    const int*   smap   = (const int*)d_in[3];
    float* out = (float*)d_out;
    int*   ws  = (int*)d_ws;

    const int N = in_sizes[0] / 2;
    const bool fused = (ws == nullptr) || (ws_size < (size_t)N * 8 * sizeof(int));

    const int waves  = (N + 1) / 2;               // 2 agents per wave
    const int blocks = (waves * 64 + 255) / 256;
    hipLaunchKernelGGL(nsp_gather, dim3(blocks), dim3(256), 0, stream,
                       cstep, fframe, cvel, smap, ws, out, fused ? 1 : 0, N);
    if (!fused) {
        hipLaunchKernelGGL(nsp_force, dim3((N + 255) / 256), dim3(256), 0, stream,
                           cstep, fframe, cvel, ws, out, N);
    }
}